// Round 14
// baseline (385.864 us; speedup 1.0000x reference)
//
#include <hip/hip_runtime.h>
#include <hip/hip_bf16.h>

// ---------------------------------------------------------------------------
// Sudoku GCN, fully fused, MFMA-everything.
//   h_{l+1} = relu( (A+I) h_l * (W_l/21) + b_l ),  A+I exact 0/1 in bf16.
// Orientation ping-pong (no transposed reads, all epi writes packed):
//   hbuf = h^T [feat][node] (chunk-major); agg: g^T = h^T (A+I);
//   gemm: h' = g (W/21); l=6: h6^T = W^T g^T -> h6 [node][feat] for out-GEMM.
// Layer 1 collapsed: h1 = relu(Cnt @ U + b1), U = relu(Win+bin)@W1/21.
// R9: 64-feat g-slices, 2 blocks/CU. R10-R13: numerics cuts (g/h/W hi-only,
// absmax 4.88e-4 vs 7.5e-4 threshold). R13 counters: MfmaUtil 39 = exactly
// the MFMA-issue floor at 16 waves/CU; NO pipe >50% -> concurrency-bound.
// R14: 24 waves/CU. 768-thr blocks (12 waves), still 2 blocks/CU (LDS 55.7K
// x2 = 111K). 6 waves/SIMD caps regs at ~85 -> per-wave tile 6->4
// (2 ntiles x 2 ftiles in EVERY phase; 24 agg jobs = 12x2, 48 W jobs =
// 12x4): abf 36->24, wc 24->16, wb per-kk 8, ubf 16. Peak ~80 regs.
// Zero numerics change (absmax must stay bit-identical).
// ---------------------------------------------------------------------------

typedef short          s16x8 __attribute__((ext_vector_type(8)));
typedef unsigned short u16x8 __attribute__((ext_vector_type(8)));
typedef unsigned short u16x4 __attribute__((ext_vector_type(4)));
typedef float          f32x4 __attribute__((ext_vector_type(4)));

#define HB    0       // hbuf: [12 nodechunk][128 feat][16B] hi only = 24576
                      // (l6: h6 as [16 fchunk][96 node][16B] = 24576, reused)
#define GS0   24576   // gslice 0: [96 node][64 feat swizzled] hi = 12288
#define GS1   36864   // gslice 1: ditto
#define CNT   49152   // cnt : [4 chunk][96 node][16B] = 6144
#define XC    55296   // x cache: 81 ints
#define LDS_SZ 55680  // x2 = 111360 <= 163840 -> 2 blocks/CU (1536 thr <= 2048)

#define OFF_WB   5120     // [l 0..4][nt 0..7][ks 0..3][pl 0..1] x 1024B
#define OFF_AB   332800   // [nt 0..5][ks 0..2] x 1024B  (A+I, hi only, exact)
#define OFF_UB   351232   // [nt 0..7][pl] x 1024B
#define OFF_WOUT 367616   // [ks 0..3][pl] x 1024B
#define WS_NEED  375808

__device__ __forceinline__ unsigned short f2bf(float f) {   // RTNE via v_cvt
  return __builtin_bit_cast(unsigned short, __float2bfloat16(f));
}
__device__ __forceinline__ float bf2f(unsigned short h) {
  unsigned u = ((unsigned)h) << 16;
  return __builtin_bit_cast(float, u);
}
__device__ __forceinline__ f32x4 mfma16(u16x8 a, u16x8 b, f32x4 c) {
  return __builtin_amdgcn_mfma_f32_16x16x32_bf16(
      __builtin_bit_cast(s16x8, a), __builtin_bit_cast(s16x8, b), c, 0, 0, 0);
}
__device__ __forceinline__ u16x4 cvt4(f32x4 v) {            // hi-only convert
  u16x4 hi;
#pragma unroll
  for (int r = 0; r < 4; ++r) hi[r] = f2bf(v[r]);
  return hi;
}
__device__ __forceinline__ bool adjf(int r, int c) {
  if (r >= 81 || c >= 81) return false;
  int ri = r / 9, rj = r % 9, ci = c / 9, cj = c % 9;
  return ri == ci || rj == cj || (ri / 3 == ci / 3 && rj / 3 == cj / 3);
}
__device__ __forceinline__ u16x8 makeAB(int nt, int ks, int lane) {
  int col = nt * 16 + (lane & 15), k0 = ks * 32 + (lane >> 4) * 8;
  u16x8 r;
#pragma unroll
  for (int i = 0; i < 8; ++i) r[i] = adjf(k0 + i, col) ? 0x3F80 : 0;
  return r;
}

// ---------------- setup1: U[10][128] = relu(Win+bin) @ W1 / 21 (f32, ws+0) ---
extern "C" __global__ void gnn_setup(const float* __restrict__ Win,
                                     const float* __restrict__ bin,
                                     const float* __restrict__ W1,
                                     float* __restrict__ U) {
  __shared__ float V[1280];
  int t = threadIdx.x;
#pragma unroll
  for (int q = 0; q < 5; ++q) {
    int idx = t + 256 * q;
    V[idx] = fmaxf(Win[idx] + bin[idx & 127], 0.f);
  }
  __syncthreads();
#pragma unroll
  for (int p = 0; p < 5; ++p) {
    int o = t + 256 * p;
    int d = o >> 7, c = o & 127;
    float s = 0.f;
    for (int f = 0; f < 128; ++f) s += V[d * 128 + f] * W1[f * 128 + c];
    U[o] = s * (1.f / 21.f);
  }
}

// ---------------- setup2: pack all B/A fragment blobs into ws ----------------
extern "C" __global__ void gnn_pack(const float* __restrict__ Wl,
                                    const float* __restrict__ Wout,
                                    const float* __restrict__ Uscr,
                                    char* __restrict__ G) {
  int unit = blockIdx.x, lane = threadIdx.x;
  int rsel = lane & 15, kh = lane >> 4;
  u16x8 r;
  char* dst;
  if (unit < 320) {                       // WB: ((l*8+nt)*4+ks)*2+pl
    int pl = unit & 1, ks = (unit >> 1) & 3, nt = (unit >> 3) & 7, l = unit >> 6;
    int col = nt * 16 + rsel, k0 = ks * 32 + kh * 8;
    const float* src = Wl + (l + 1) * 16384 + k0 * 128 + col;
#pragma unroll
    for (int i = 0; i < 8; ++i) {
      float v = src[i * 128] * (1.f / 21.f);
      unsigned short h = f2bf(v);
      r[i] = pl ? f2bf(v - bf2f(h)) : h;
    }
    dst = G + OFF_WB + unit * 1024 + lane * 16;
  } else if (unit < 338) {                // AB: nt*3+ks
    int u2 = unit - 320, nt = u2 / 3, ks = u2 % 3;
    r = makeAB(nt, ks, lane);
    dst = G + OFF_AB + u2 * 1024 + lane * 16;
  } else if (unit < 354) {                // UB: nt*2+pl
    int u2 = unit - 338, nt = u2 >> 1, pl = u2 & 1;
    int col = nt * 16 + rsel;
#pragma unroll
    for (int i = 0; i < 8; ++i) {
      int k = kh * 8 + i;
      float v = (k < 10) ? Uscr[k * 128 + col] : 0.f;
      unsigned short h = f2bf(v);
      r[i] = pl ? f2bf(v - bf2f(h)) : h;
    }
    dst = G + OFF_UB + u2 * 1024 + lane * 16;
  } else {                                // WOUT: ks*2+pl
    int u2 = unit - 354, ks = u2 >> 1, pl = u2 & 1;
    int col = rsel, k0 = ks * 32 + kh * 8;
#pragma unroll
    for (int i = 0; i < 8; ++i) {
      float v = (col < 9) ? Wout[(k0 + i) * 9 + col] : 0.f;
      unsigned short h = f2bf(v);
      r[i] = pl ? f2bf(v - bf2f(h)) : h;
    }
    dst = G + OFF_WOUT + u2 * 1024 + lane * 16;
  }
  *(u16x8*)dst = r;
}

// --------------------------------- main -------------------------------------
template <bool PRE>
__global__ void __launch_bounds__(768, 6)
gnn_main(const int* __restrict__ x, const float* __restrict__ Wl,
         const float* __restrict__ bl, const float* __restrict__ Wout,
         const float* __restrict__ bout, const float* __restrict__ ws,
         float* __restrict__ out, int nB) {
  extern __shared__ char lds[];
  const int t = threadIdx.x, lane = t & 63, w = t >> 6;   // w 0..11
  const int rsel = lane & 15, kh = lane >> 4;
  const char* G = (const char*)ws;
  const int b = blockIdx.x;

  const int npair = w % 3;               // ntiles npair*2 + {0,1}
  const int fts = w / 3;                 // 0..3: out ftiles fts*2+{0,1};
                                         // agg ftile (per slice s) = s*4+fts

  // ---- persistent A+I B-frags (exact, hi only): 2 ntiles x 3 ks = 24 regs --
  u16x8 abf[2][3];
#pragma unroll
  for (int jn = 0; jn < 2; ++jn)
#pragma unroll
    for (int ks = 0; ks < 3; ++ks) {
      if constexpr (PRE)
        abf[jn][ks] = *(const u16x8*)(G + OFF_AB + (((npair * 2 + jn) * 3 + ks) << 10) + lane * 16);
      else
        abf[jn][ks] = makeAB(npair * 2 + jn, ks, lane);
    }

  // per-k-chunk W frags, HI ONLY: [jf] = 2 frags = 8 regs
  u16x8 wb[2];
  auto loadWBkk = [&](int blob, int s, int kk) {
#pragma unroll
    for (int jf = 0; jf < 2; ++jf) {
      if constexpr (PRE) {
        wb[jf] = *(const u16x8*)(
            G + OFF_WB +
            ((((blob * 8 + (fts * 2 + jf)) * 4 + (s * 2 + kk)) * 2) << 10) +
            lane * 16);
      } else {
        int colw = (fts * 2 + jf) * 16 + rsel, k0 = (s * 2 + kk) * 32 + kh * 8;
        const float* src = Wl + (blob + 1) * 16384 + k0 * 128 + colw;
        u16x8 r;
#pragma unroll
        for (int i = 0; i < 8; ++i) r[i] = f2bf(src[i * 128] * (1.f / 21.f));
        wb[jf] = r;
      }
    }
  };

  // ---- x cache + digit counts -> cntbuf ----
  if (t < 81) ((int*)(lds + XC))[t] = x[b * 81 + t];
  __syncthreads();
  if (t < 96) {
    unsigned short cnt[16];
#pragma unroll
    for (int d = 0; d < 16; ++d) cnt[d] = 0;
    if (t < 81) {
      const int* xs = (const int*)(lds + XC);
      int n = t, i = n / 9, j = n - 9 * i;
      int bi = (i / 3) * 3, bj = (j / 3) * 3;
      int rv[9], cv[9], bv[9], rb3[3], cb3[3];
#pragma unroll
      for (int k = 0; k < 9; ++k) rv[k] = xs[i * 9 + k];
#pragma unroll
      for (int k = 0; k < 9; ++k) cv[k] = xs[k * 9 + j];
#pragma unroll
      for (int r2 = 0; r2 < 3; ++r2)
#pragma unroll
        for (int c2 = 0; c2 < 3; ++c2) bv[r2 * 3 + c2] = xs[(bi + r2) * 9 + (bj + c2)];
#pragma unroll
      for (int k = 0; k < 3; ++k) rb3[k] = xs[i * 9 + bj + k];
#pragma unroll
      for (int k = 0; k < 3; ++k) cb3[k] = xs[(bi + k) * 9 + j];
#pragma unroll
      for (int d = 0; d < 10; ++d) {
        int c = 0;
#pragma unroll
        for (int k = 0; k < 9; ++k) c += (rv[k] == d) + (cv[k] == d) + (bv[k] == d);
#pragma unroll
        for (int k = 0; k < 3; ++k) c -= (rb3[k] == d) + (cb3[k] == d);
        cnt[d] = f2bf((float)c);         // integers <=21: exact in bf16
      }
    }
    u16x8 c0, c1, z;
#pragma unroll
    for (int e = 0; e < 8; ++e) { c0[e] = cnt[e]; c1[e] = cnt[8 + e]; z[e] = 0; }
    *(u16x8*)(lds + CNT + 0 * 1536 + t * 16) = c0;
    *(u16x8*)(lds + CNT + 1 * 1536 + t * 16) = c1;
    *(u16x8*)(lds + CNT + 2 * 1536 + t * 16) = z;
    *(u16x8*)(lds + CNT + 3 * 1536 + t * 16) = z;
  }
  __syncthreads();

  // ---- L1 GEMM: h1 = relu(Cnt @ U + b1) -> hbuf [feat][node] (2x2 tiles) ---
  {
    u16x8 ubf[2][2];                     // [jf][pl], dead after L1
#pragma unroll
    for (int jf = 0; jf < 2; ++jf)
#pragma unroll
      for (int pl = 0; pl < 2; ++pl) {
        if constexpr (PRE)
          ubf[jf][pl] = *(const u16x8*)(G + OFF_UB + (((fts * 2 + jf) * 2 + pl) << 10) + lane * 16);
        else {
          int col = (fts * 2 + jf) * 16 + rsel;
          u16x8 r;
#pragma unroll
          for (int i = 0; i < 8; ++i) {
            int k = kh * 8 + i;
            float v = (k < 10) ? ws[k * 128 + col] : 0.f;
            unsigned short h = f2bf(v);
            r[i] = pl ? f2bf(v - bf2f(h)) : h;
          }
          ubf[jf][pl] = r;
        }
      }
    float bL1[2];
#pragma unroll
    for (int jf = 0; jf < 2; ++jf) bL1[jf] = bl[(fts * 2 + jf) * 16 + rsel];

    f32x4 a1[2][2];
#pragma unroll
    for (int jn = 0; jn < 2; ++jn)
#pragma unroll
      for (int jf = 0; jf < 2; ++jf) a1[jn][jf] = f32x4{0.f, 0.f, 0.f, 0.f};
#pragma unroll
    for (int jn = 0; jn < 2; ++jn) {
      int node = (npair * 2 + jn) * 16 + rsel;
      u16x8 af = *(const u16x8*)(lds + CNT + kh * 1536 + node * 16);
#pragma unroll
      for (int jf = 0; jf < 2; ++jf) {
        a1[jn][jf] = mfma16(af, ubf[jf][0], a1[jn][jf]);
        a1[jn][jf] = mfma16(af, ubf[jf][1], a1[jn][jf]);
      }
    }
#pragma unroll
    for (int jn = 0; jn < 2; ++jn)
#pragma unroll
      for (int jf = 0; jf < 2; ++jf) {
        int node0 = (npair * 2 + jn) * 16 + kh * 4;
        int feat = (fts * 2 + jf) * 16 + rsel;
        f32x4 v;
#pragma unroll
        for (int r = 0; r < 4; ++r) {
          float u = fmaxf(a1[jn][jf][r] + bL1[jf], 0.f);
          v[r] = (node0 + r < 81) ? u : 0.f;
        }
        int base = (node0 >> 3) * 2048 + feat * 16 + (node0 & 7) * 2;
        *(u16x4*)(lds + HB + base) = cvt4(v);
      }
  }

  // agg of one 64-feat slice -> GS0/GS1 (1-product: h hi-only, A exact)
  auto do_agg_slice = [&](int s) {
    f32x4 ag[2];
#pragma unroll
    for (int jn = 0; jn < 2; ++jn) ag[jn] = f32x4{0.f, 0.f, 0.f, 0.f};
    int feat = (s * 4 + fts) * 16 + rsel;
#pragma unroll
    for (int ks = 0; ks < 3; ++ks) {
      int ba = (ks * 4 + kh) * 2048 + feat * 16;
      u16x8 ah = *(const u16x8*)(lds + HB + ba);
#pragma unroll
      for (int jn = 0; jn < 2; ++jn) ag[jn] = mfma16(ah, abf[jn][ks], ag[jn]);
    }
    int gsb = GS0 + s * 12288;
    int wbase = fts * 16 + kh * 4;       // within-slice floc base
    int wfb = wbase >> 3, woff = (wbase & 7) * 2;
#pragma unroll
    for (int jn = 0; jn < 2; ++jn) {
      int node = (npair * 2 + jn) * 16 + rsel;
      int ad = node * 128 + (((wfb + node) & 7) << 4) + woff;
      *(u16x4*)(lds + gsb + ad) = cvt4(ag[jn]);
    }
  };

  // W accumulate one slice from GS[s] (1-product: g hi x W hi)
  f32x4 wc[2][2];
  auto do_W_slice = [&](int blob, int s) {
    int gsb = GS0 + s * 12288;
#pragma unroll
    for (int kk = 0; kk < 2; ++kk) {
#pragma unroll
      for (int jm = 0; jm < 2; ++jm) {
        int node = (npair * 2 + jm) * 16 + rsel;
        int ad = node * 128 + (((4 * kk + kh + node) & 7) << 4);
        u16x8 gh = *(const u16x8*)(lds + gsb + ad);
#pragma unroll
        for (int jf = 0; jf < 2; ++jf)
          wc[jm][jf] = mfma16(gh, wb[jf], wc[jm][jf]);
      }
      if (kk == 0) loadWBkk(blob, s, 1);     // reuse wb regs (WAR, sequential)
    }
  };

  // ---- GCN layers 2..5 (l=1..4): 2 slices, GS double-buffered, 3 barriers --
#pragma unroll 1
  for (int l = 1; l <= 4; ++l) {
    __syncthreads();                     // HB ready (prev epi)
    float bw[2];
#pragma unroll
    for (int jf = 0; jf < 2; ++jf) bw[jf] = bl[l * 128 + (fts * 2 + jf) * 16 + rsel];
#pragma unroll
    for (int jm = 0; jm < 2; ++jm)
#pragma unroll
      for (int jf = 0; jf < 2; ++jf) wc[jm][jf] = f32x4{0.f, 0.f, 0.f, 0.f};

    do_agg_slice(0);                     // -> GS0
    loadWBkk(l - 1, 0, 0);               // hides under agg + barrier
    __syncthreads();                     // GS0 ready
    do_agg_slice(1);                     // -> GS1 (interleaves with W(0))
    do_W_slice(l - 1, 0);                // reads GS0
    loadWBkk(l - 1, 1, 0);               // after W(0): wb regs free (WAR)
    __syncthreads();                     // GS1 ready (also: all HB reads done)
    do_W_slice(l - 1, 1);                // reads GS1
    // epi: bias+relu+mask -> hbuf [feat][node] hi-only
#pragma unroll
    for (int jm = 0; jm < 2; ++jm)
#pragma unroll
      for (int jf = 0; jf < 2; ++jf) {
        int node0 = (npair * 2 + jm) * 16 + kh * 4;
        int feat = (fts * 2 + jf) * 16 + rsel;
        f32x4 v;
#pragma unroll
        for (int r = 0; r < 4; ++r) {
          float u = fmaxf(wc[jm][jf][r] + bw[jf], 0.f);
          v[r] = (node0 + r < 81) ? u : 0.f;
        }
        int base = (node0 >> 3) * 2048 + feat * 16 + (node0 & 7) * 2;
        *(u16x4*)(lds + HB + base) = cvt4(v);
      }
  }

  // ---- layer 6 (l=5), flipped: h6^T = (W/21)^T g^T, same 3-barrier shape ---
  __syncthreads();                       // HB (h5) ready
  {
    float b5[2][4];
#pragma unroll
    for (int jf = 0; jf < 2; ++jf)
#pragma unroll
      for (int r = 0; r < 4; ++r)
        b5[jf][r] = bl[5 * 128 + (fts * 2 + jf) * 16 + kh * 4 + r];
    f32x4 w6[2][2];
#pragma unroll
    for (int jf = 0; jf < 2; ++jf)
#pragma unroll
      for (int jn = 0; jn < 2; ++jn) w6[jf][jn] = f32x4{0.f, 0.f, 0.f, 0.f};

    auto do_flip_slice = [&](int s) {
      int gsb = GS0 + s * 12288;
#pragma unroll
      for (int kk = 0; kk < 2; ++kk) {
#pragma unroll
        for (int jn = 0; jn < 2; ++jn) {
          int node = (npair * 2 + jn) * 16 + rsel;
          int ad = node * 128 + (((4 * kk + kh + node) & 7) << 4);
          u16x8 gh = *(const u16x8*)(lds + gsb + ad);
#pragma unroll
          for (int jf = 0; jf < 2; ++jf)
            w6[jf][jn] = mfma16(wb[jf], gh, w6[jf][jn]);
        }
        if (kk == 0) loadWBkk(4, s, 1);
      }
    };

    do_agg_slice(0);
    loadWBkk(4, 0, 0);
    __syncthreads();                     // GS0 ready
    do_agg_slice(1);
    do_flip_slice(0);
    loadWBkk(4, 1, 0);                   // after flip(0): wb regs free
    __syncthreads();                     // GS1 ready (all HB h5 reads done)
    do_flip_slice(1);
    // epi: C row=feat_out(4 consec), col=node -> h6 [node][feat] into HB
#pragma unroll
    for (int jf = 0; jf < 2; ++jf)
#pragma unroll
      for (int jn = 0; jn < 2; ++jn) {
        int node = (npair * 2 + jn) * 16 + rsel;
        int f0 = (fts * 2 + jf) * 16 + kh * 4;
        f32x4 v;
#pragma unroll
        for (int r = 0; r < 4; ++r) {
          float u = fmaxf(w6[jf][jn][r] + b5[jf][r], 0.f);
          v[r] = (node < 81) ? u : 0.f;
        }
        int base = (f0 >> 3) * 1536 + node * 16 + (f0 & 7) * 2;
        *(u16x4*)(lds + HB + base) = cvt4(v);
      }
  }

  // ---- output GEMM: logits = h6 @ Wout + bout (waves 0..5, 1 tile each) ----
  u16x8 wo[4][2];
  if (w < 6) {
#pragma unroll
    for (int ks = 0; ks < 4; ++ks)
#pragma unroll
      for (int pl = 0; pl < 2; ++pl) {
        if constexpr (PRE)
          wo[ks][pl] = *(const u16x8*)(G + OFF_WOUT + (ks * 2 + pl) * 1024 + lane * 16);
        else {
          int col = rsel, k0 = ks * 32 + kh * 8;
          u16x8 r;
#pragma unroll
          for (int i = 0; i < 8; ++i) {
            float v = (col < 9) ? Wout[(k0 + i) * 9 + col] : 0.f;
            unsigned short h = f2bf(v);
            r[i] = pl ? f2bf(v - bf2f(h)) : h;
          }
          wo[ks][pl] = r;
        }
      }
  }
  __syncthreads();
  if (w < 6) {
    f32x4 oc = f32x4{0.f, 0.f, 0.f, 0.f};
#pragma unroll
    for (int ks = 0; ks < 4; ++ks) {
      int node = w * 16 + rsel;
      int ba = (ks * 4 + kh) * 1536 + node * 16;
      u16x8 hh = *(const u16x8*)(lds + HB + ba);
      oc = mfma16(hh, wo[ks][0], oc);
      oc = mfma16(hh, wo[ks][1], oc);
    }
    int colo = rsel;
    if (colo < 9) {
      float bo = bout[colo];
#pragma unroll
      for (int r = 0; r < 4; ++r) {
        int node = w * 16 + kh * 4 + r;
        if (node < 81) out[b * 729 + node * 9 + colo] = oc[r] + bo;
      }
    }
  }
}

// ------------------------------- launcher ------------------------------------
extern "C" void kernel_launch(void* const* d_in, const int* in_sizes, int n_in,
                              void* d_out, int out_size, void* d_ws, size_t ws_size,
                              hipStream_t stream) {
  const int*   x    = (const int*)d_in[0];
  const float* Win  = (const float*)d_in[1];
  const float* bin  = (const float*)d_in[2];
  const float* Wl   = (const float*)d_in[3];
  const float* blay = (const float*)d_in[4];
  const float* Wout = (const float*)d_in[5];
  const float* bout = (const float*)d_in[6];
  float* out = (float*)d_out;
  int nB = in_sizes[0] / 81;

  bool pre = ws_size >= WS_NEED;
  gnn_setup<<<1, 256, 0, stream>>>(Win, bin, Wl, (float*)d_ws);     // U -> ws+0
  if (pre)
    gnn_pack<<<362, 64, 0, stream>>>(Wl, Wout, (const float*)d_ws, (char*)d_ws);

  if (pre) {
    hipFuncSetAttribute((const void*)gnn_main<true>,
                        hipFuncAttributeMaxDynamicSharedMemorySize, LDS_SZ);
    gnn_main<true><<<nB, 768, LDS_SZ, stream>>>(x, Wl, blay, Wout, bout,
                                                (const float*)d_ws, out, nB);
  } else {
    hipFuncSetAttribute((const void*)gnn_main<false>,
                        hipFuncAttributeMaxDynamicSharedMemorySize, LDS_SZ);
    gnn_main<false><<<nB, 768, LDS_SZ, stream>>>(x, Wl, blay, Wout, bout,
                                                 (const float*)d_ws, out, nB);
  }
}